// Round 9
// baseline (302.602 us; speedup 1.0000x reference)
//
#include <hip/hip_runtime.h>
#include <hip/hip_bf16.h>
#include <math.h>

// GAT 2-layer fused pipeline for MI355X (gfx950).
// Round-18: revert r17's 2-deep gat pipeline (compiler re-serialized it;
// VGPR stayed 48, perf -3us). Keep r15 gat body (best: 46.4us). New:
// eliminate the Mhi/Mlo inter-kernel round-trips (~102MB):
//  - gemm_fused01 = layer0 GEMM + gelu + layer1 q/p projections in ONE
//    kernel; m1 lives only in LDS (stage->K1->gelu->LDS->K2->epilogue).
//  - gat_gemm2 = layer1 GAT (64 nodes/block, 4 passes) + layer2 q/p
//    projections; m2 lives only in LDS. Outputs q2/p2 go to the now-free
//    Mhi/Mlo regions (no hazard with q_buf/pb still being gathered).
// gat inner math, CSR chain, pack_w byte-identical to r15 -> bitwise-
// identical output. Launches 13 -> 10.

#define SLOPE 0.2f

typedef __attribute__((ext_vector_type(8))) __bf16 bf16x8;
typedef __attribute__((ext_vector_type(4))) float f32x4;

__device__ __forceinline__ float gelu_erf(float x) {
    return 0.5f * x * (1.0f + erff(x * 0.70710678118654752f));
}

__device__ __forceinline__ unsigned short f2bf(float f) {  // RNE
    unsigned int u = __float_as_uint(f);
    return (unsigned short)((u + 0x7fffu + ((u >> 16) & 1u)) >> 16);
}
__device__ __forceinline__ float bf2f(unsigned short h) {
    return __uint_as_float((unsigned int)h << 16);
}

// 16-lane (row) all-reduce sum via DPP row_ror 1,2,4,8.
__device__ __forceinline__ float row16_sum(float x) {
    x += __int_as_float(__builtin_amdgcn_update_dpp(0, __float_as_int(x), 0x121, 0xF, 0xF, true));
    x += __int_as_float(__builtin_amdgcn_update_dpp(0, __float_as_int(x), 0x122, 0xF, 0xF, true));
    x += __int_as_float(__builtin_amdgcn_update_dpp(0, __float_as_int(x), 0x124, 0xF, 0xF, true));
    x += __int_as_float(__builtin_amdgcn_update_dpp(0, __float_as_int(x), 0x128, 0xF, 0xF, true));
    return x;
}

// XOR swizzle for LDS planes with 256B row stride.
__device__ __forceinline__ int swz(int off) { return off ^ ((off >> 4) & 0x70); }

// ---------------- weight prepack ---------------------------------------------
__global__ __launch_bounds__(256) void pack_w(
    const float* __restrict__ W0,  const float* __restrict__ Wq1,
    const float* __restrict__ Wp1, const float* __restrict__ Wq2,
    const float* __restrict__ Wp2,
    unsigned short* __restrict__ P0,  unsigned short* __restrict__ Pq1,
    unsigned short* __restrict__ Pp1, unsigned short* __restrict__ Pq2,
    unsigned short* __restrict__ Pp2)
{
    const float* W; unsigned short* P; int C;
    switch (blockIdx.y) {
        case 0:  W = W0;  P = P0;  C = 128; break;
        case 1:  W = Wq1; P = Pq1; C = 128; break;
        case 2:  W = Wp1; P = Pp1; C = 128; break;
        case 3:  W = Wq2; P = Pq2; C = 64;  break;
        default: W = Wp2; P = Pp2; C = 64;  break;
    }
    int i = blockIdx.x * 256 + threadIdx.x;
    int CE = C * 128;
    if (i >= CE) return;
    int j = i & 7, l = (i >> 3) & 63, ks = (i >> 9) & 3, ct = i >> 11;
    int k = ks * 32 + ((l >> 4) << 3) + j;
    int n = ct * 16 + (l & 15);
    float v = W[k * C + n];
    unsigned short hb = f2bf(v);
    P[i] = hb;
    P[CE + i] = f2bf(v - bf2f(hb));
}

// ---------------- fused layer0 GEMM + gelu + layer1 projections --------------
// Block = 64 rows. Stage x -> LDS (hi/lo bf16) -> K-loop1 (W0) -> gelu ->
// m1 into LDS -> K-loop2 over {Wq1, Wp1} (16 col-tiles / 4 waves) ->
// q1 fp32 direct stores, p1 bf16 via LDS bounce. m1 never hits global.
__global__ __launch_bounds__(256) void gemm_fused01(
    const float* __restrict__ x,
    const unsigned short* __restrict__ P0,  const float* __restrict__ b0,
    const unsigned short* __restrict__ Pq1, const float* __restrict__ bq1,
    const unsigned short* __restrict__ Pp1, const float* __restrict__ bp1,
    float* __restrict__ outq, unsigned short* __restrict__ outp, int N)
{
    constexpr int CE = 128 * 128;
    __shared__ __align__(16) unsigned char lds[32768]; // hi [0,16K), lo [16K,32K)

    const int t = threadIdx.x;
    const int lane = t & 63;
    const int w = t >> 6;
    const int row0 = blockIdx.x * 64;
    const int mcol = lane & 15;
    const int hk = lane >> 4;

    // ---- stage x (64 x 128 f32) as hi/lo bf16 into LDS ----
#pragma unroll
    for (int i = 0; i < 8; i++) {
        int idx = t + i * 256;            // float4 index, 2048 total
        int row = idx >> 5;
        int gr = row0 + row;
        float4 v = make_float4(0.f, 0.f, 0.f, 0.f);
        if (gr < N) v = *reinterpret_cast<const float4*>(x + (size_t)gr * 128 + (idx & 31) * 4);
        const float* f = reinterpret_cast<const float*>(&v);
        unsigned int h[4], l[4];
#pragma unroll
        for (int j = 0; j < 4; j++) {
            unsigned short hb = f2bf(f[j]);
            h[j] = hb;
            l[j] = f2bf(f[j] - bf2f(hb));
        }
        int so = swz(row * 256 + (idx & 31) * 8);
        *reinterpret_cast<uint2*>(&lds[so])         = make_uint2(h[0] | (h[1] << 16), h[2] | (h[3] << 16));
        *reinterpret_cast<uint2*>(&lds[16384 + so]) = make_uint2(l[0] | (l[1] << 16), l[2] | (l[3] << 16));
    }
    __syncthreads();

    // ---- K-loop 1: m1 = x @ W0 (C=128, 8 tiles / 4 waves -> CTW=2) ----
    f32x4 acc1[2][4];
#pragma unroll
    for (int c = 0; c < 2; c++)
#pragma unroll
        for (int rf = 0; rf < 4; rf++) acc1[c][rf] = (f32x4){0.f, 0.f, 0.f, 0.f};

#pragma unroll
    for (int ks = 0; ks < 4; ks++) {
        bf16x8 ah[4], al[4];
#pragma unroll
        for (int rf = 0; rf < 4; rf++) {
            int so = swz((rf * 16 + mcol) * 256 + ks * 64 + hk * 16);
            ah[rf] = *reinterpret_cast<const bf16x8*>(&lds[so]);
            al[rf] = *reinterpret_cast<const bf16x8*>(&lds[16384 + so]);
        }
#pragma unroll
        for (int c = 0; c < 2; c++) {
            int ct = w * 2 + c;
            const unsigned short* Wp = P0 + ((ct * 4 + ks) * 64 + lane) * 8;
            bf16x8 bh = *reinterpret_cast<const bf16x8*>(Wp);
            bf16x8 bl = *reinterpret_cast<const bf16x8*>(Wp + CE);
#pragma unroll
            for (int rf = 0; rf < 4; rf++) {
                acc1[c][rf] = __builtin_amdgcn_mfma_f32_16x16x32_bf16(ah[rf], bh, acc1[c][rf], 0, 0, 0);
                acc1[c][rf] = __builtin_amdgcn_mfma_f32_16x16x32_bf16(al[rf], bh, acc1[c][rf], 0, 0, 0);
                acc1[c][rf] = __builtin_amdgcn_mfma_f32_16x16x32_bf16(ah[rf], bl, acc1[c][rf], 0, 0, 0);
            }
        }
    }
    __syncthreads();   // all K1 ds_reads done

    // ---- m1 = gelu(acc1 + b0) -> LDS hi/lo (C/D layout col=lane&15, row=hk*4+r)
#pragma unroll
    for (int c = 0; c < 2; c++) {
        int col = (w * 2 + c) * 16 + mcol;
        float bv = b0[col];
#pragma unroll
        for (int rf = 0; rf < 4; rf++) {
#pragma unroll
            for (int r = 0; r < 4; r++) {
                int row = rf * 16 + hk * 4 + r;
                float v = gelu_erf(acc1[c][rf][r] + bv);
                unsigned short hb = f2bf(v);
                int bo = row * 256 + col * 2;
                *reinterpret_cast<unsigned short*>(&lds[swz(bo)])         = hb;
                *reinterpret_cast<unsigned short*>(&lds[16384 + swz(bo)]) = f2bf(v - bf2f(hb));
            }
        }
    }
    __syncthreads();

    // ---- K-loop 2: {q1, p1} = m1 @ {Wq1, Wp1} (16 tiles / 4 waves -> CTW=4)
    f32x4 acc2[4][4];
#pragma unroll
    for (int c = 0; c < 4; c++)
#pragma unroll
        for (int rf = 0; rf < 4; rf++) acc2[c][rf] = (f32x4){0.f, 0.f, 0.f, 0.f};

#pragma unroll
    for (int ks = 0; ks < 4; ks++) {
        bf16x8 ah[4], al[4];
#pragma unroll
        for (int rf = 0; rf < 4; rf++) {
            int so = swz((rf * 16 + mcol) * 256 + ks * 64 + hk * 16);
            ah[rf] = *reinterpret_cast<const bf16x8*>(&lds[so]);
            al[rf] = *reinterpret_cast<const bf16x8*>(&lds[16384 + so]);
        }
#pragma unroll
        for (int c = 0; c < 4; c++) {
            int ctg = w * 4 + c;
            bool isq = ctg < 8;
            int ct = isq ? ctg : ctg - 8;
            const unsigned short* Wp = (isq ? Pq1 : Pp1) + ((ct * 4 + ks) * 64 + lane) * 8;
            bf16x8 bh = *reinterpret_cast<const bf16x8*>(Wp);
            bf16x8 bl = *reinterpret_cast<const bf16x8*>(Wp + CE);
#pragma unroll
            for (int rf = 0; rf < 4; rf++) {
                acc2[c][rf] = __builtin_amdgcn_mfma_f32_16x16x32_bf16(ah[rf], bh, acc2[c][rf], 0, 0, 0);
                acc2[c][rf] = __builtin_amdgcn_mfma_f32_16x16x32_bf16(al[rf], bh, acc2[c][rf], 0, 0, 0);
                acc2[c][rf] = __builtin_amdgcn_mfma_f32_16x16x32_bf16(ah[rf], bl, acc2[c][rf], 0, 0, 0);
            }
        }
    }
    __syncthreads();   // all K2 ds_reads done; LDS reused for p1 bounce

    // ---- epilogue: q1 fp32 direct; p1 bf16 -> LDS bounce -> 16B stores ----
#pragma unroll
    for (int c = 0; c < 4; c++) {
        int ctg = w * 4 + c;
        bool isq = ctg < 8;
        int ct = isq ? ctg : ctg - 8;
        int col = ct * 16 + mcol;
        float bv = (isq ? bq1 : bp1)[col];
#pragma unroll
        for (int rf = 0; rf < 4; rf++) {
#pragma unroll
            for (int r = 0; r < 4; r++) {
                int row = rf * 16 + hk * 4 + r;
                int gr = row0 + row;
                float v = acc2[c][rf][r] + bv;
                if (isq) {
                    if (gr < N) outq[(size_t)gr * 128 + col] = v;
                } else {
                    *reinterpret_cast<unsigned short*>(&lds[swz(row * 256 + col * 2)]) = f2bf(v);
                }
            }
        }
    }
    __syncthreads();
#pragma unroll
    for (int i = 0; i < 4; i++) {
        int idx = t + i * 256;          // 1024 uint4 (64 rows x 16 slots)
        int row = idx >> 4;
        int sl = idx & 15;
        int gr = row0 + row;
        if (gr < N)
            *reinterpret_cast<uint4*>(outp + (size_t)gr * 128 + sl * 8) =
                *reinterpret_cast<const uint4*>(&lds[swz(row * 256 + sl * 16)]);
    }
}

// ---------------- CSR build: atomic-free two-level counting sort -------------

__global__ __launch_bounds__(256) void hist_coarse(
    const int* __restrict__ dst, int* __restrict__ gh, int E, int CB)
{
    __shared__ int cnt[4096];
    const int blk = blockIdx.x;     // 0..63
    const int t = threadIdx.x;
    for (int b = t; b < CB; b += 256) cnt[b] = 0;
    __syncthreads();
    const int epb = (E + 63) / 64;
    const int s = blk * epb;
    const int e_ = (s + epb < E) ? s + epb : E;
    for (int i = s + t; i < e_; i += 256)
        atomicAdd(&cnt[dst[i] >> 4], 1);
    __syncthreads();
    for (int b = t; b < CB; b += 256)
        gh[b * 64 + blk] = cnt[b];
}

__global__ __launch_bounds__(256) void scan1_kernel(const int* __restrict__ gh,
                                                    int* __restrict__ gscan,
                                                    int* __restrict__ bsum, int M)
{
    __shared__ int lds[256];
    int t = threadIdx.x;
    int i = blockIdx.x * 256 + t;
    int v = (i < M) ? gh[i] : 0;
    lds[t] = v;
    __syncthreads();
    int x = v;
    for (int off = 1; off < 256; off <<= 1) {
        int y = (t >= off) ? lds[t - off] : 0;
        __syncthreads();
        x += y;
        lds[t] = x;
        __syncthreads();
    }
    if (i < M) gscan[i] = x - v;
    if (t == 255) bsum[blockIdx.x] = x;
}

__global__ __launch_bounds__(1024) void scan2_kernel(int* __restrict__ bsum, int NB)
{
    __shared__ int lds[1024];
    int t = threadIdx.x;
    int v = (t < NB) ? bsum[t] : 0;
    lds[t] = v;
    __syncthreads();
    int x = v;
    for (int off = 1; off < 1024; off <<= 1) {
        int y = (t >= off) ? lds[t - off] : 0;
        __syncthreads();
        x += y;
        lds[t] = x;
        __syncthreads();
    }
    if (t < NB) bsum[t] = x - v;
}

__global__ __launch_bounds__(256) void scan3_kernel(int* __restrict__ gscan,
                                                    const int* __restrict__ bsum, int M)
{
    int i = blockIdx.x * 256 + threadIdx.x;
    if (i < M) gscan[i] += bsum[blockIdx.x];
}

__global__ __launch_bounds__(256) void scatter_coarse(
    const int* __restrict__ src, const int* __restrict__ dst,
    const int* __restrict__ gscan, int2* __restrict__ pairs, int E, int CB)
{
    __shared__ int cur[4096];
    const int blk = blockIdx.x;     // 0..63
    const int t = threadIdx.x;
    for (int b = t; b < CB; b += 256)
        cur[b] = gscan[b * 64 + blk];
    __syncthreads();
    const int epb = (E + 63) / 64;
    const int s = blk * epb;
    const int e_ = (s + epb < E) ? s + epb : E;
    for (int i = s + t; i < e_; i += 256) {
        int d = dst[i];
        int sv = src[i];
        int pos = atomicAdd(&cur[d >> 4], 1);   // LDS atomic
        pairs[pos] = make_int2(d, sv);
    }
}

// one WAVE per coarse bin: ballot-histogram counts, stable ranks. No atomics.
__global__ __launch_bounds__(256) void finalize_kernel(
    const int2* __restrict__ pairs, const int* __restrict__ gscan,
    int* __restrict__ offs, int* __restrict__ csr_src, int N, int E, int CB)
{
    const int wid = blockIdx.x * 4 + (threadIdx.x >> 6);   // bin index
    const int lane = threadIdx.x & 63;
    if (wid >= CB) return;                                 // wave-uniform exit

    const int s    = gscan[wid * 64];
    const int e_   = (wid + 1 < CB) ? gscan[(wid + 1) * 64] : E;
    const int base = wid * 16;
    const unsigned long long ltmask = (lane == 63) ? ~0ull >> 1
                                                   : (1ull << lane) - 1ull;

    int rc[16];
#pragma unroll
    for (int j = 0; j < 16; j++) rc[j] = 0;
    for (int c0 = s; c0 < e_; c0 += 64) {
        int i = c0 + lane;
        int d = (i < e_) ? pairs[i].x - base : -1;
#pragma unroll
        for (int j = 0; j < 16; j++)
            rc[j] += (int)__popcll(__ballot(d == j));
    }

    int pref[16];
    int run = s;
#pragma unroll
    for (int j = 0; j < 16; j++) { pref[j] = run; run += rc[j]; }
    int pref_v = 0;
#pragma unroll
    for (int j = 0; j < 16; j++) pref_v = (lane == j) ? pref[j] : pref_v;

    if (lane < 16 && base + lane < N) offs[base + lane] = pref_v;
    if (wid == CB - 1 && lane == 16) offs[N] = E;

    int rcv = 0;
    for (int c0 = s; c0 < e_; c0 += 64) {
        int i = c0 + lane;
        const bool act = i < e_;
        int2 pr = act ? pairs[i] : make_int2(base - 1, 0);
        int d = pr.x - base;
        unsigned long long msel = 0;
        int addcnt = 0;
#pragma unroll
        for (int j = 0; j < 16; j++) {
            unsigned long long m = __ballot(d == j);
            if (d == j) msel = m;
            if (lane == j) addcnt = (int)__popcll(m);
        }
        int subrank = (int)__popcll(msel & ltmask);
        int posbase = __builtin_amdgcn_ds_bpermute(d * 4, pref_v + rcv);
        if (act) csr_src[posbase + subrank] = pr.y;
        rcv += addcnt;
    }
}

// ---------------- fused layer1 GAT + layer2 projections ----------------------
// Block = 64 nodes (4 passes x 4 waves x 4 nodes). Per pass: r15 gat body
// (16 lanes/node, 4-edge MLP + next-batch gather pipeline); m2 = gelu
// written straight into LDS (hi/lo, zeros for invalid rows). Then GEMM
// C=64 over {Wq2, Wp2} (8 tiles / 4 waves); q2 fp32 direct (64B lines),
// p2 bf16 LDS-bounce. m2 never hits global.
__global__ __launch_bounds__(256) void gat_gemm2(
    const float* __restrict__ q, const unsigned short* __restrict__ p,
    const float* __restrict__ a, const float* __restrict__ bg2,
    const int* __restrict__ offs, const int* __restrict__ csr_src,
    const unsigned short* __restrict__ Pq2, const float* __restrict__ bq2,
    const unsigned short* __restrict__ Pp2, const float* __restrict__ bp2,
    float* __restrict__ outq2, unsigned short* __restrict__ outp2, int N)
{
    constexpr int CE = 64 * 128;
    __shared__ __align__(16) unsigned char lds[32768];

    const int t = threadIdx.x;
    const int lane = t & 63;
    const int w = t >> 6;
    const int sl = lane & 15;
    const int base = sl * 8;       // 8 dims/lane (D=128)
    const int row0 = blockIdx.x * 64;

    float a6[8], a4[8];
#pragma unroll
    for (int v = 0; v < 8; v++) {
        float av = a[base + v];
        a6[v] = 0.6f * av;
        a4[v] = 0.4f * av;
    }

    auto gather = [&](int s) -> uint4 {
        return *reinterpret_cast<const uint4*>(p + (size_t)s * 128 + base);
    };
    auto unpack = [&](uint4 u, float* pv) {
        pv[0] = __uint_as_float(u.x << 16); pv[1] = __uint_as_float(u.x & 0xffff0000u);
        pv[2] = __uint_as_float(u.y << 16); pv[3] = __uint_as_float(u.y & 0xffff0000u);
        pv[4] = __uint_as_float(u.z << 16); pv[5] = __uint_as_float(u.z & 0xffff0000u);
        pv[6] = __uint_as_float(u.w << 16); pv[7] = __uint_as_float(u.w & 0xffff0000u);
    };

    // ---- phase 1: GAT over 4 passes (16 nodes/pass) ----
    for (int pass = 0; pass < 4; pass++) {
        const int row = pass * 16 + w * 4 + (lane >> 4);
        const int node = row0 + row;
        const bool valid = node < N;

        float qv[8], acc[8];
#pragma unroll
        for (int v = 0; v < 8; v++) { qv[v] = 0.f; acc[v] = 0.f; }
        if (valid) {
            const float* qp = q + (size_t)node * 128 + base;
            float4 q0 = *reinterpret_cast<const float4*>(qp);
            float4 q1 = *reinterpret_cast<const float4*>(qp + 4);
            qv[0] = q0.x; qv[1] = q0.y; qv[2] = q0.z; qv[3] = q0.w;
            qv[4] = q1.x; qv[5] = q1.y; qv[6] = q1.z; qv[7] = q1.w;
        }

        float denom = 0.f;
        int e  = valid ? offs[node] : 0;
        int e1 = valid ? offs[node + 1] : 0;

        int s0 = csr_src[(e + 0 < e1) ? e + 0 : 0];
        int s1 = csr_src[(e + 1 < e1) ? e + 1 : 0];
        int s2 = csr_src[(e + 2 < e1) ? e + 2 : 0];
        int s3 = csr_src[(e + 3 < e1) ? e + 3 : 0];
        uint4 uA0 = gather(s0), uA1 = gather(s1), uA2 = gather(s2), uA3 = gather(s3);
        int en = e + 4;
        int n0 = csr_src[(en + 0 < e1) ? en + 0 : 0];
        int n1 = csr_src[(en + 1 < e1) ? en + 1 : 0];
        int n2 = csr_src[(en + 2 < e1) ? en + 2 : 0];
        int n3 = csr_src[(en + 3 < e1) ? en + 3 : 0];

        while (__any(e < e1)) {
            const bool a0 = (e + 0) < e1, a1b = (e + 1) < e1,
                       a2 = (e + 2) < e1, a3 = (e + 3) < e1;

            uint4 v0 = gather(n0), v1 = gather(n1), v2 = gather(n2), v3 = gather(n3);

            const int em = en + 4;
            const int m0 = csr_src[(em + 0 < e1) ? em + 0 : 0];
            const int m1 = csr_src[(em + 1 < e1) ? em + 1 : 0];
            const int m2 = csr_src[(em + 2 < e1) ? em + 2 : 0];
            const int m3 = csr_src[(em + 3 < e1) ? em + 3 : 0];

            float pv[4][8];
            unpack(uA0, pv[0]); unpack(uA1, pv[1]); unpack(uA2, pv[2]); unpack(uA3, pv[3]);

            float pa0 = 0.f, pa1 = 0.f, pa2 = 0.f, pa3 = 0.f;
#pragma unroll
            for (int v = 0; v < 8; v++) {
                float d0 = qv[v] + pv[0][v];
                float d1 = qv[v] + pv[1][v];
                float d2 = qv[v] + pv[2][v];
                float d3 = qv[v] + pv[3][v];
                pa0 = fmaf(d0, a6[v], pa0); pa0 = fmaf(fabsf(d0), a4[v], pa0);
                pa1 = fmaf(d1, a6[v], pa1); pa1 = fmaf(fabsf(d1), a4[v], pa1);
                pa2 = fmaf(d2, a6[v], pa2); pa2 = fmaf(fabsf(d2), a4[v], pa2);
                pa3 = fmaf(d3, a6[v], pa3); pa3 = fmaf(fabsf(d3), a4[v], pa3);
            }

            float r0 = row16_sum(pa0);
            float r1 = row16_sum(pa1);
            float r2 = row16_sum(pa2);
            float r3 = row16_sum(pa3);

            float esm0 = a0  ? __expf(r0) : 0.f;
            float esm1 = a1b ? __expf(r1) : 0.f;
            float esm2 = a2  ? __expf(r2) : 0.f;
            float esm3 = a3  ? __expf(r3) : 0.f;
            denom += (esm0 + esm1) + (esm2 + esm3);
#pragma unroll
            for (int v = 0; v < 8; v++) {
                acc[v] = fmaf(esm0, pv[0][v], acc[v]);
                acc[v] = fmaf(esm1, pv[1][v], acc[v]);
                acc[v] = fmaf(esm2, pv[2][v], acc[v]);
                acc[v] = fmaf(esm3, pv[3][v], acc[v]);
            }

            uA0 = v0; uA1 = v1; uA2 = v2; uA3 = v3;
            n0 = m0; n1 = m1; n2 = m2; n3 = m3;
            e = en; en = em;
        }

        // m2 = gelu(agg + bg2) -> LDS hi/lo (zeros for invalid rows)
        float inv = (denom != 0.f) ? 1.f / denom : 0.f;
        union { unsigned short us[8]; uint4 v; } H, L;
#pragma unroll
        for (int v = 0; v < 8; v++) {
            if (valid) {
                float g = gelu_erf(acc[v] * inv + bg2[base + v]);
                H.us[v] = f2bf(g);
                L.us[v] = f2bf(g - bf2f(H.us[v]));
            } else {
                H.us[v] = 0; L.us[v] = 0;
            }
        }
        int so = swz(row * 256 + sl * 16);
        *reinterpret_cast<uint4*>(&lds[so])         = H.v;
        *reinterpret_cast<uint4*>(&lds[16384 + so]) = L.v;
    }
    __syncthreads();

    // ---- phase 2: {q2, p2} = m2 @ {Wq2, Wp2} (C=64, 8 tiles / 4 waves) ----
    const int mcol = sl;
    const int hk = lane >> 4;
    f32x4 acc2[2][4];
#pragma unroll
    for (int c = 0; c < 2; c++)
#pragma unroll
        for (int rf = 0; rf < 4; rf++) acc2[c][rf] = (f32x4){0.f, 0.f, 0.f, 0.f};

#pragma unroll
    for (int ks = 0; ks < 4; ks++) {
        bf16x8 ah[4], al[4];
#pragma unroll
        for (int rf = 0; rf < 4; rf++) {
            int so = swz((rf * 16 + mcol) * 256 + ks * 64 + hk * 16);
            ah[rf] = *reinterpret_cast<const bf16x8*>(&lds[so]);
            al[rf] = *reinterpret_cast<const bf16x8*>(&lds[16384 + so]);
        }
#pragma unroll
        for (int c = 0; c < 2; c++) {
            int ctg = w * 2 + c;
            bool isq = ctg < 4;
            int ct = isq ? ctg : ctg - 4;
            const unsigned short* Wp = (isq ? Pq2 : Pp2) + ((ct * 4 + ks) * 64 + lane) * 8;
            bf16x8 bh = *reinterpret_cast<const bf16x8*>(Wp);
            bf16x8 bl = *reinterpret_cast<const bf16x8*>(Wp + CE);
#pragma unroll
            for (int rf = 0; rf < 4; rf++) {
                acc2[c][rf] = __builtin_amdgcn_mfma_f32_16x16x32_bf16(ah[rf], bh, acc2[c][rf], 0, 0, 0);
                acc2[c][rf] = __builtin_amdgcn_mfma_f32_16x16x32_bf16(al[rf], bh, acc2[c][rf], 0, 0, 0);
                acc2[c][rf] = __builtin_amdgcn_mfma_f32_16x16x32_bf16(ah[rf], bl, acc2[c][rf], 0, 0, 0);
            }
        }
    }
    __syncthreads();   // K2 ds_reads done; LDS reused for p2 bounce

    // ---- epilogue: q2 fp32 direct; p2 bf16 -> LDS bounce -> 16B stores ----
#pragma unroll
    for (int c = 0; c < 2; c++) {
        int ctg = w * 2 + c;
        bool isq = ctg < 4;
        int ct = isq ? ctg : ctg - 4;
        int col = ct * 16 + mcol;
        float bv = (isq ? bq2 : bp2)[col];
#pragma unroll
        for (int rf = 0; rf < 4; rf++) {
#pragma unroll
            for (int r = 0; r < 4; r++) {
                int row = rf * 16 + hk * 4 + r;
                int gr = row0 + row;
                float v = acc2[c][rf][r] + bv;
                if (isq) {
                    if (gr < N) outq2[(size_t)gr * 64 + col] = v;
                } else {
                    *reinterpret_cast<unsigned short*>(&lds[swz(row * 256 + col * 2)]) = f2bf(v);
                }
            }
        }
    }
    __syncthreads();
#pragma unroll
    for (int i = 0; i < 2; i++) {
        int idx = t + i * 256;          // 512 uint4 (64 rows x 8 slots)
        int row = idx >> 3;
        int sl8 = idx & 7;
        int gr = row0 + row;
        if (gr < N)
            *reinterpret_cast<uint4*>(outp2 + (size_t)gr * 64 + sl8 * 8) =
                *reinterpret_cast<const uint4*>(&lds[swz(row * 256 + sl8 * 16)]);
    }
}

// ---------------- layer2 GAT (D=64, fp32 out) --------------------------------
// r15 form: 16 lanes/node, 4 nodes/wave, 4-edge MLP + next-batch pipeline.
__global__ __launch_bounds__(256) void gat_agg64(
    const float* __restrict__ q, const unsigned short* __restrict__ p,
    const float* __restrict__ a, const float* __restrict__ bvec,
    const int* __restrict__ offs, const int* __restrict__ csr_src,
    float* __restrict__ out, int N)
{
    const int t = threadIdx.x;
    const int lane = t & 63;
    const int sl = lane & 15;
    const int base = sl * 4;
    const int node = blockIdx.x * 16 + ((t >> 6) << 2) + (lane >> 4);
    const bool valid = node < N;

    float qv[4], a6[4], a4[4], acc[4];
#pragma unroll
    for (int v = 0; v < 4; v++) { qv[v] = 0.f; acc[v] = 0.f; }
    if (valid) {
        float4 q0 = *reinterpret_cast<const float4*>(q + (size_t)node * 64 + base);
        qv[0] = q0.x; qv[1] = q0.y; qv[2] = q0.z; qv[3] = q0.w;
    }
#pragma unroll
    for (int v = 0; v < 4; v++) {
        float av = a[base + v];
        a6[v] = 0.6f * av;
        a4[v] = 0.4f * av;
    }

    auto gather = [&](int s) -> uint2 {
        return *reinterpret_cast<const uint2*>(p + (size_t)s * 64 + base);
    };
    auto unpack = [&](uint2 u, float* pv) {
        pv[0] = __uint_as_float(u.x << 16); pv[1] = __uint_as_float(u.x & 0xffff0000u);
        pv[2] = __uint_as_float(u.y << 16); pv[3] = __uint_as_float(u.y & 0xffff0000u);
    };

    float denom = 0.f;
    int e  = valid ? offs[node] : 0;
    int e1 = valid ? offs[node + 1] : 0;

    int s0 = csr_src[(e + 0 < e1) ? e + 0 : 0];
    int s1 = csr_src[(e + 1 < e1) ? e + 1 : 0];
    int s2 = csr_src[(e + 2 < e1) ? e + 2 : 0];
    int s3 = csr_src[(e + 3 < e1) ? e + 3 : 0];
    uint2 uA0 = gather(s0), uA1 = gather(s1), uA2 = gather(s2), uA3 = gather(s3);
    int en = e + 4;
    int n0 = csr_src[(en + 0 < e1) ? en + 0 : 0];
    int n1 = csr_src[(en + 1 < e1) ? en + 1 : 0];
    int n2 = csr_src[(en + 2 < e1) ? en + 2 : 0];
    int n3 = csr_src[(en + 3 < e1) ? en + 3 : 0];

    while (__any(e < e1)) {
        const bool a0 = (e + 0) < e1, a1b = (e + 1) < e1,
                   a2 = (e + 2) < e1, a3 = (e + 3) < e1;

        uint2 v0 = gather(n0), v1 = gather(n1), v2 = gather(n2), v3 = gather(n3);

        const int em = en + 4;
        const int m0 = csr_src[(em + 0 < e1) ? em + 0 : 0];
        const int m1 = csr_src[(em + 1 < e1) ? em + 1 : 0];
        const int m2 = csr_src[(em + 2 < e1) ? em + 2 : 0];
        const int m3 = csr_src[(em + 3 < e1) ? em + 3 : 0];

        float pv[4][4];
        unpack(uA0, pv[0]); unpack(uA1, pv[1]); unpack(uA2, pv[2]); unpack(uA3, pv[3]);

        float pa0 = 0.f, pa1 = 0.f, pa2 = 0.f, pa3 = 0.f;
#pragma unroll
        for (int v = 0; v < 4; v++) {
            float d0 = qv[v] + pv[0][v];
            float d1 = qv[v] + pv[1][v];
            float d2 = qv[v] + pv[2][v];
            float d3 = qv[v] + pv[3][v];
            pa0 = fmaf(d0, a6[v], pa0); pa0 = fmaf(fabsf(d0), a4[v], pa0);
            pa1 = fmaf(d1, a6[v], pa1); pa1 = fmaf(fabsf(d1), a4[v], pa1);
            pa2 = fmaf(d2, a6[v], pa2); pa2 = fmaf(fabsf(d2), a4[v], pa2);
            pa3 = fmaf(d3, a6[v], pa3); pa3 = fmaf(fabsf(d3), a4[v], pa3);
        }

        float r0 = row16_sum(pa0);
        float r1 = row16_sum(pa1);
        float r2 = row16_sum(pa2);
        float r3 = row16_sum(pa3);

        float esm0 = a0  ? __expf(r0) : 0.f;
        float esm1 = a1b ? __expf(r1) : 0.f;
        float esm2 = a2  ? __expf(r2) : 0.f;
        float esm3 = a3  ? __expf(r3) : 0.f;
        denom += (esm0 + esm1) + (esm2 + esm3);
#pragma unroll
        for (int v = 0; v < 4; v++) {
            acc[v] = fmaf(esm0, pv[0][v], acc[v]);
            acc[v] = fmaf(esm1, pv[1][v], acc[v]);
            acc[v] = fmaf(esm2, pv[2][v], acc[v]);
            acc[v] = fmaf(esm3, pv[3][v], acc[v]);
        }

        uA0 = v0; uA1 = v1; uA2 = v2; uA3 = v3;
        n0 = m0; n1 = m1; n2 = m2; n3 = m3;
        e = en; en = em;
    }

    if (!valid) return;
    float inv = (denom != 0.f) ? 1.f / denom : 0.f;
    union { float f[4]; float4 v; } O;
#pragma unroll
    for (int v = 0; v < 4; v++) O.f[v] = acc[v] * inv + bvec[base + v];
    *reinterpret_cast<float4*>(out + (size_t)node * 64 + base) = O.v;
}

// ---------------- launch ------------------------------------------------------
extern "C" void kernel_launch(void* const* d_in, const int* in_sizes, int n_in,
                              void* d_out, int out_size, void* d_ws, size_t ws_size,
                              hipStream_t stream)
{
    const float* x     = (const float*)d_in[0];
    const float* W0    = (const float*)d_in[1];
    const float* b0    = (const float*)d_in[2];
    const float* Wq1   = (const float*)d_in[3];
    const float* bq1   = (const float*)d_in[4];
    const float* Wp1   = (const float*)d_in[5];
    const float* bp1   = (const float*)d_in[6];
    const float* a1    = (const float*)d_in[7];
    const float* bg2   = (const float*)d_in[8];
    const float* Wq2   = (const float*)d_in[9];
    const float* bq2   = (const float*)d_in[10];
    const float* Wp2   = (const float*)d_in[11];
    const float* bp2   = (const float*)d_in[12];
    const float* a2    = (const float*)d_in[13];
    const float* b_out = (const float*)d_in[14];
    const int*   src   = (const int*)d_in[15];
    const int*   dst   = (const int*)d_in[16];

    const int N = in_sizes[0] / 128;
    const int E = in_sizes[15];
    float* out = (float*)d_out;

    // workspace carve
    float* q_buf        = (float*)d_ws;                      // N*128 f32 (q1)
    unsigned short* pb  = (unsigned short*)(q_buf + (size_t)N * 128);  // N*128 bf16 (p1)
    unsigned short* Mhi = pb + (size_t)N * 128;              // reused: q2 = N*64 f32
    unsigned short* Mlo = Mhi + (size_t)N * 128;             // reused: p2 = N*64 bf16
    unsigned short* P0  = Mlo + (size_t)N * 128;
    unsigned short* Pq1 = P0  + 128 * 128 * 2;
    unsigned short* Pp1 = Pq1 + 128 * 128 * 2;
    unsigned short* Pq2 = Pp1 + 128 * 128 * 2;
    unsigned short* Pp2 = Pq2 + 128 * 64 * 2;
    int* offs    = (int*)(Pp2 + 128 * 64 * 2);
    int* csr_src = offs + (N + 2);
    const int CB = (N + 15) / 16;          // coarse bins
    const int M  = CB * 64;
    int* gh    = csr_src + E;
    int* gscan = gh + M;
    int* bsum  = gscan + M;                // 1024 ints
    // pairs aliases q_buf (dead before gemm_fused01 writes q1)
    int2* pairs = (int2*)q_buf;
    float* q2f = (float*)Mhi;              // N*64 f32 (16B-aligned: offsets are
    unsigned short* p2b = Mlo;             //   multiples of N*128*2 bytes)

    const int NB1 = (M + 255) / 256;       // <= 1024

    // 1) weight prepack
    pack_w<<<dim3(64, 5), 256, 0, stream>>>(W0, Wq1, Wp1, Wq2, Wp2,
                                            P0, Pq1, Pp1, Pq2, Pp2);
    // 2-7) CSR build (atomic-free two-level counting sort)
    hist_coarse<<<64, 256, 0, stream>>>(dst, gh, E, CB);
    scan1_kernel<<<NB1, 256, 0, stream>>>(gh, gscan, bsum, M);
    scan2_kernel<<<1, 1024, 0, stream>>>(bsum, NB1);
    scan3_kernel<<<NB1, 256, 0, stream>>>(gscan, bsum, M);
    scatter_coarse<<<64, 256, 0, stream>>>(src, dst, gscan, pairs, E, CB);
    finalize_kernel<<<(CB + 3) / 4, 256, 0, stream>>>(pairs, gscan, offs, csr_src, N, E, CB);

    const int GB64 = (N + 63) / 64;

    // 8) layer0 GEMM + gelu + layer1 projections (m1 stays in LDS)
    gemm_fused01<<<GB64, 256, 0, stream>>>(
        x, P0, b0, Pq1, bq1, Pp1, bp1, q_buf, pb, N);
    // 9) layer1 GAT + layer2 projections (m2 stays in LDS) -> q2/p2
    gat_gemm2<<<GB64, 256, 0, stream>>>(
        q_buf, pb, a1, bg2, offs, csr_src,
        Pq2, bq2, Pp2, bp2, q2f, p2b, N);
    // 10) layer2 GAT + b_out -> d_out
    gat_agg64<<<(N + 15) / 16, 256, 0, stream>>>(
        q2f, p2b, a2, b_out, offs, csr_src, out, N);
}

// Round 10
// 279.382 us; speedup vs baseline: 1.0831x; 1.0831x over previous
//
#include <hip/hip_runtime.h>
#include <hip/hip_bf16.h>
#include <math.h>

// GAT 2-layer fused pipeline for MI355X (gfx950).
// Round-19: keep r18's gemm_fused01 (L0+L1 in one kernel, m1 LDS-only:
// measured ~-6us), REVERT r18's gat_gemm2 fusion (86us vs 61us it
// replaced: 32KB LDS + VGPR76 dropped occupancy 38->18.8%, block barrier
// waits on max-degree-of-64-nodes; fusing across a latency-bound phase
// loses more occupancy/imbalance than it saves in traffic). gat128 back
// to r15 form (best: 46.4us, 0 LDS, 38% occ) -> Mhi/Mlo; L2 projections
// back to r15's mfma_gemm<64>. All parts byte-identical to r15/r18 ->
// bitwise-identical output.

#define SLOPE 0.2f

typedef __attribute__((ext_vector_type(8))) __bf16 bf16x8;
typedef __attribute__((ext_vector_type(4))) float f32x4;

__device__ __forceinline__ float gelu_erf(float x) {
    return 0.5f * x * (1.0f + erff(x * 0.70710678118654752f));
}

__device__ __forceinline__ unsigned short f2bf(float f) {  // RNE
    unsigned int u = __float_as_uint(f);
    return (unsigned short)((u + 0x7fffu + ((u >> 16) & 1u)) >> 16);
}
__device__ __forceinline__ float bf2f(unsigned short h) {
    return __uint_as_float((unsigned int)h << 16);
}

// 16-lane (row) all-reduce sum via DPP row_ror 1,2,4,8.
__device__ __forceinline__ float row16_sum(float x) {
    x += __int_as_float(__builtin_amdgcn_update_dpp(0, __float_as_int(x), 0x121, 0xF, 0xF, true));
    x += __int_as_float(__builtin_amdgcn_update_dpp(0, __float_as_int(x), 0x122, 0xF, 0xF, true));
    x += __int_as_float(__builtin_amdgcn_update_dpp(0, __float_as_int(x), 0x124, 0xF, 0xF, true));
    x += __int_as_float(__builtin_amdgcn_update_dpp(0, __float_as_int(x), 0x128, 0xF, 0xF, true));
    return x;
}

// XOR swizzle for LDS planes with 256B row stride.
__device__ __forceinline__ int swz(int off) { return off ^ ((off >> 4) & 0x70); }

// ---------------- weight prepack ---------------------------------------------
__global__ __launch_bounds__(256) void pack_w(
    const float* __restrict__ W0,  const float* __restrict__ Wq1,
    const float* __restrict__ Wp1, const float* __restrict__ Wq2,
    const float* __restrict__ Wp2,
    unsigned short* __restrict__ P0,  unsigned short* __restrict__ Pq1,
    unsigned short* __restrict__ Pp1, unsigned short* __restrict__ Pq2,
    unsigned short* __restrict__ Pp2)
{
    const float* W; unsigned short* P; int C;
    switch (blockIdx.y) {
        case 0:  W = W0;  P = P0;  C = 128; break;
        case 1:  W = Wq1; P = Pq1; C = 128; break;
        case 2:  W = Wp1; P = Pp1; C = 128; break;
        case 3:  W = Wq2; P = Pq2; C = 64;  break;
        default: W = Wp2; P = Pp2; C = 64;  break;
    }
    int i = blockIdx.x * 256 + threadIdx.x;
    int CE = C * 128;
    if (i >= CE) return;
    int j = i & 7, l = (i >> 3) & 63, ks = (i >> 9) & 3, ct = i >> 11;
    int k = ks * 32 + ((l >> 4) << 3) + j;
    int n = ct * 16 + (l & 15);
    float v = W[k * C + n];
    unsigned short hb = f2bf(v);
    P[i] = hb;
    P[CE + i] = f2bf(v - bf2f(hb));
}

// ---------------- fused layer0 GEMM + gelu + layer1 projections --------------
// Block = 64 rows. Stage x -> LDS (hi/lo bf16) -> K-loop1 (W0) -> gelu ->
// m1 into LDS -> K-loop2 over {Wq1, Wp1} (16 col-tiles / 4 waves) ->
// q1 fp32 direct stores, p1 bf16 via LDS bounce. m1 never hits global.
__global__ __launch_bounds__(256) void gemm_fused01(
    const float* __restrict__ x,
    const unsigned short* __restrict__ P0,  const float* __restrict__ b0,
    const unsigned short* __restrict__ Pq1, const float* __restrict__ bq1,
    const unsigned short* __restrict__ Pp1, const float* __restrict__ bp1,
    float* __restrict__ outq, unsigned short* __restrict__ outp, int N)
{
    constexpr int CE = 128 * 128;
    __shared__ __align__(16) unsigned char lds[32768]; // hi [0,16K), lo [16K,32K)

    const int t = threadIdx.x;
    const int lane = t & 63;
    const int w = t >> 6;
    const int row0 = blockIdx.x * 64;
    const int mcol = lane & 15;
    const int hk = lane >> 4;

    // ---- stage x (64 x 128 f32) as hi/lo bf16 into LDS ----
#pragma unroll
    for (int i = 0; i < 8; i++) {
        int idx = t + i * 256;            // float4 index, 2048 total
        int row = idx >> 5;
        int gr = row0 + row;
        float4 v = make_float4(0.f, 0.f, 0.f, 0.f);
        if (gr < N) v = *reinterpret_cast<const float4*>(x + (size_t)gr * 128 + (idx & 31) * 4);
        const float* f = reinterpret_cast<const float*>(&v);
        unsigned int h[4], l[4];
#pragma unroll
        for (int j = 0; j < 4; j++) {
            unsigned short hb = f2bf(f[j]);
            h[j] = hb;
            l[j] = f2bf(f[j] - bf2f(hb));
        }
        int so = swz(row * 256 + (idx & 31) * 8);
        *reinterpret_cast<uint2*>(&lds[so])         = make_uint2(h[0] | (h[1] << 16), h[2] | (h[3] << 16));
        *reinterpret_cast<uint2*>(&lds[16384 + so]) = make_uint2(l[0] | (l[1] << 16), l[2] | (l[3] << 16));
    }
    __syncthreads();

    // ---- K-loop 1: m1 = x @ W0 (C=128, 8 tiles / 4 waves -> CTW=2) ----
    f32x4 acc1[2][4];
#pragma unroll
    for (int c = 0; c < 2; c++)
#pragma unroll
        for (int rf = 0; rf < 4; rf++) acc1[c][rf] = (f32x4){0.f, 0.f, 0.f, 0.f};

#pragma unroll
    for (int ks = 0; ks < 4; ks++) {
        bf16x8 ah[4], al[4];
#pragma unroll
        for (int rf = 0; rf < 4; rf++) {
            int so = swz((rf * 16 + mcol) * 256 + ks * 64 + hk * 16);
            ah[rf] = *reinterpret_cast<const bf16x8*>(&lds[so]);
            al[rf] = *reinterpret_cast<const bf16x8*>(&lds[16384 + so]);
        }
#pragma unroll
        for (int c = 0; c < 2; c++) {
            int ct = w * 2 + c;
            const unsigned short* Wp = P0 + ((ct * 4 + ks) * 64 + lane) * 8;
            bf16x8 bh = *reinterpret_cast<const bf16x8*>(Wp);
            bf16x8 bl = *reinterpret_cast<const bf16x8*>(Wp + CE);
#pragma unroll
            for (int rf = 0; rf < 4; rf++) {
                acc1[c][rf] = __builtin_amdgcn_mfma_f32_16x16x32_bf16(ah[rf], bh, acc1[c][rf], 0, 0, 0);
                acc1[c][rf] = __builtin_amdgcn_mfma_f32_16x16x32_bf16(al[rf], bh, acc1[c][rf], 0, 0, 0);
                acc1[c][rf] = __builtin_amdgcn_mfma_f32_16x16x32_bf16(ah[rf], bl, acc1[c][rf], 0, 0, 0);
            }
        }
    }
    __syncthreads();   // all K1 ds_reads done

    // ---- m1 = gelu(acc1 + b0) -> LDS hi/lo ----
#pragma unroll
    for (int c = 0; c < 2; c++) {
        int col = (w * 2 + c) * 16 + mcol;
        float bv = b0[col];
#pragma unroll
        for (int rf = 0; rf < 4; rf++) {
#pragma unroll
            for (int r = 0; r < 4; r++) {
                int row = rf * 16 + hk * 4 + r;
                float v = gelu_erf(acc1[c][rf][r] + bv);
                unsigned short hb = f2bf(v);
                int bo = row * 256 + col * 2;
                *reinterpret_cast<unsigned short*>(&lds[swz(bo)])         = hb;
                *reinterpret_cast<unsigned short*>(&lds[16384 + swz(bo)]) = f2bf(v - bf2f(hb));
            }
        }
    }
    __syncthreads();

    // ---- K-loop 2: {q1, p1} = m1 @ {Wq1, Wp1} (16 tiles / 4 waves) ----
    f32x4 acc2[4][4];
#pragma unroll
    for (int c = 0; c < 4; c++)
#pragma unroll
        for (int rf = 0; rf < 4; rf++) acc2[c][rf] = (f32x4){0.f, 0.f, 0.f, 0.f};

#pragma unroll
    for (int ks = 0; ks < 4; ks++) {
        bf16x8 ah[4], al[4];
#pragma unroll
        for (int rf = 0; rf < 4; rf++) {
            int so = swz((rf * 16 + mcol) * 256 + ks * 64 + hk * 16);
            ah[rf] = *reinterpret_cast<const bf16x8*>(&lds[so]);
            al[rf] = *reinterpret_cast<const bf16x8*>(&lds[16384 + so]);
        }
#pragma unroll
        for (int c = 0; c < 4; c++) {
            int ctg = w * 4 + c;
            bool isq = ctg < 8;
            int ct = isq ? ctg : ctg - 8;
            const unsigned short* Wp = (isq ? Pq1 : Pp1) + ((ct * 4 + ks) * 64 + lane) * 8;
            bf16x8 bh = *reinterpret_cast<const bf16x8*>(Wp);
            bf16x8 bl = *reinterpret_cast<const bf16x8*>(Wp + CE);
#pragma unroll
            for (int rf = 0; rf < 4; rf++) {
                acc2[c][rf] = __builtin_amdgcn_mfma_f32_16x16x32_bf16(ah[rf], bh, acc2[c][rf], 0, 0, 0);
                acc2[c][rf] = __builtin_amdgcn_mfma_f32_16x16x32_bf16(al[rf], bh, acc2[c][rf], 0, 0, 0);
                acc2[c][rf] = __builtin_amdgcn_mfma_f32_16x16x32_bf16(ah[rf], bl, acc2[c][rf], 0, 0, 0);
            }
        }
    }
    __syncthreads();   // all K2 ds_reads done; LDS reused for p1 bounce

    // ---- epilogue: q1 fp32 direct; p1 bf16 -> LDS bounce -> 16B stores ----
#pragma unroll
    for (int c = 0; c < 4; c++) {
        int ctg = w * 4 + c;
        bool isq = ctg < 8;
        int ct = isq ? ctg : ctg - 8;
        int col = ct * 16 + mcol;
        float bv = (isq ? bq1 : bp1)[col];
#pragma unroll
        for (int rf = 0; rf < 4; rf++) {
#pragma unroll
            for (int r = 0; r < 4; r++) {
                int row = rf * 16 + hk * 4 + r;
                int gr = row0 + row;
                float v = acc2[c][rf][r] + bv;
                if (isq) {
                    if (gr < N) outq[(size_t)gr * 128 + col] = v;
                } else {
                    *reinterpret_cast<unsigned short*>(&lds[swz(row * 256 + col * 2)]) = f2bf(v);
                }
            }
        }
    }
    __syncthreads();
#pragma unroll
    for (int i = 0; i < 4; i++) {
        int idx = t + i * 256;          // 1024 uint4 (64 rows x 16 slots)
        int row = idx >> 4;
        int sl = idx & 15;
        int gr = row0 + row;
        if (gr < N)
            *reinterpret_cast<uint4*>(outp + (size_t)gr * 128 + sl * 8) =
                *reinterpret_cast<const uint4*>(&lds[swz(row * 256 + sl * 16)]);
    }
}

// ---------------- MFMA GEMM (layer-2 projections, C=64, two matrices) --------
__global__ __launch_bounds__(256) void mfma_gemm64(
    const unsigned short* __restrict__ AHg, const unsigned short* __restrict__ ALg,
    const unsigned short* __restrict__ P1, const float* __restrict__ b1,
    const unsigned short* __restrict__ P2, const float* __restrict__ b2,
    float* __restrict__ outq, unsigned short* __restrict__ outp, int N)
{
    constexpr int CE = 64 * 128;
    __shared__ __align__(16) unsigned char lds[32768];

    const int t = threadIdx.x;
    const int lane = t & 63;
    const int w = t >> 6;
    const int row0 = blockIdx.x * 64;
    const int mcol = lane & 15;
    const int hk = lane >> 4;

#pragma unroll
    for (int i = 0; i < 4; i++) {
        int idx = t + i * 256;            // uint4 index, 1024 per plane
        int row = idx >> 4;
        int gr = row0 + row;
        uint4 vh = make_uint4(0, 0, 0, 0), vl = make_uint4(0, 0, 0, 0);
        if (gr < N) {
            vh = *reinterpret_cast<const uint4*>(AHg + (size_t)gr * 128 + (idx & 15) * 8);
            vl = *reinterpret_cast<const uint4*>(ALg + (size_t)gr * 128 + (idx & 15) * 8);
        }
        int so = swz(row * 256 + (idx & 15) * 16);
        *reinterpret_cast<uint4*>(&lds[so])         = vh;
        *reinterpret_cast<uint4*>(&lds[16384 + so]) = vl;
    }
    __syncthreads();

    f32x4 acc[2][4];
#pragma unroll
    for (int c = 0; c < 2; c++)
#pragma unroll
        for (int rf = 0; rf < 4; rf++) acc[c][rf] = (f32x4){0.f, 0.f, 0.f, 0.f};

#pragma unroll
    for (int ks = 0; ks < 4; ks++) {
        bf16x8 ah[4], al[4];
#pragma unroll
        for (int rf = 0; rf < 4; rf++) {
            int so = swz((rf * 16 + mcol) * 256 + ks * 64 + hk * 16);
            ah[rf] = *reinterpret_cast<const bf16x8*>(&lds[so]);
            al[rf] = *reinterpret_cast<const bf16x8*>(&lds[16384 + so]);
        }
#pragma unroll
        for (int c = 0; c < 2; c++) {
            int ctg = w * 2 + c;
            bool isq = ctg < 4;
            int ct = isq ? ctg : ctg - 4;
            const unsigned short* Wp = (isq ? P1 : P2) + ((ct * 4 + ks) * 64 + lane) * 8;
            bf16x8 bh = *reinterpret_cast<const bf16x8*>(Wp);
            bf16x8 bl = *reinterpret_cast<const bf16x8*>(Wp + CE);
#pragma unroll
            for (int rf = 0; rf < 4; rf++) {
                acc[c][rf] = __builtin_amdgcn_mfma_f32_16x16x32_bf16(ah[rf], bh, acc[c][rf], 0, 0, 0);
                acc[c][rf] = __builtin_amdgcn_mfma_f32_16x16x32_bf16(al[rf], bh, acc[c][rf], 0, 0, 0);
                acc[c][rf] = __builtin_amdgcn_mfma_f32_16x16x32_bf16(ah[rf], bl, acc[c][rf], 0, 0, 0);
            }
        }
    }
    __syncthreads();

#pragma unroll
    for (int c = 0; c < 2; c++) {
        int ctg = w * 2 + c;
        bool isq = ctg < 4;
        int ct = isq ? ctg : ctg - 4;
        int col = ct * 16 + mcol;
        float bv = (isq ? b1 : b2)[col];
#pragma unroll
        for (int rf = 0; rf < 4; rf++) {
#pragma unroll
            for (int r = 0; r < 4; r++) {
                int row = rf * 16 + hk * 4 + r;
                int gr = row0 + row;
                float v = acc[c][rf][r] + bv;
                if (isq) {
                    if (gr < N) outq[(size_t)gr * 64 + col] = v;
                } else {
                    *reinterpret_cast<unsigned short*>(&lds[swz(row * 256 + col * 2)]) = f2bf(v);
                }
            }
        }
    }
    __syncthreads();
#pragma unroll
    for (int i = 0; i < 2; i++) {
        int idx = t + i * 256;          // 512 uint4 (64 rows x 8 slots)
        int row = idx >> 3;
        int sl = idx & 7;
        int gr = row0 + row;
        if (gr < N)
            *reinterpret_cast<uint4*>(outp + (size_t)gr * 64 + sl * 8) =
                *reinterpret_cast<const uint4*>(&lds[swz(row * 256 + sl * 16)]);
    }
}

// ---------------- CSR build: atomic-free two-level counting sort -------------

__global__ __launch_bounds__(256) void hist_coarse(
    const int* __restrict__ dst, int* __restrict__ gh, int E, int CB)
{
    __shared__ int cnt[4096];
    const int blk = blockIdx.x;     // 0..63
    const int t = threadIdx.x;
    for (int b = t; b < CB; b += 256) cnt[b] = 0;
    __syncthreads();
    const int epb = (E + 63) / 64;
    const int s = blk * epb;
    const int e_ = (s + epb < E) ? s + epb : E;
    for (int i = s + t; i < e_; i += 256)
        atomicAdd(&cnt[dst[i] >> 4], 1);
    __syncthreads();
    for (int b = t; b < CB; b += 256)
        gh[b * 64 + blk] = cnt[b];
}

__global__ __launch_bounds__(256) void scan1_kernel(const int* __restrict__ gh,
                                                    int* __restrict__ gscan,
                                                    int* __restrict__ bsum, int M)
{
    __shared__ int lds[256];
    int t = threadIdx.x;
    int i = blockIdx.x * 256 + t;
    int v = (i < M) ? gh[i] : 0;
    lds[t] = v;
    __syncthreads();
    int x = v;
    for (int off = 1; off < 256; off <<= 1) {
        int y = (t >= off) ? lds[t - off] : 0;
        __syncthreads();
        x += y;
        lds[t] = x;
        __syncthreads();
    }
    if (i < M) gscan[i] = x - v;
    if (t == 255) bsum[blockIdx.x] = x;
}

__global__ __launch_bounds__(1024) void scan2_kernel(int* __restrict__ bsum, int NB)
{
    __shared__ int lds[1024];
    int t = threadIdx.x;
    int v = (t < NB) ? bsum[t] : 0;
    lds[t] = v;
    __syncthreads();
    int x = v;
    for (int off = 1; off < 1024; off <<= 1) {
        int y = (t >= off) ? lds[t - off] : 0;
        __syncthreads();
        x += y;
        lds[t] = x;
        __syncthreads();
    }
    if (t < NB) bsum[t] = x - v;
}

__global__ __launch_bounds__(256) void scan3_kernel(int* __restrict__ gscan,
                                                    const int* __restrict__ bsum, int M)
{
    int i = blockIdx.x * 256 + threadIdx.x;
    if (i < M) gscan[i] += bsum[blockIdx.x];
}

__global__ __launch_bounds__(256) void scatter_coarse(
    const int* __restrict__ src, const int* __restrict__ dst,
    const int* __restrict__ gscan, int2* __restrict__ pairs, int E, int CB)
{
    __shared__ int cur[4096];
    const int blk = blockIdx.x;     // 0..63
    const int t = threadIdx.x;
    for (int b = t; b < CB; b += 256)
        cur[b] = gscan[b * 64 + blk];
    __syncthreads();
    const int epb = (E + 63) / 64;
    const int s = blk * epb;
    const int e_ = (s + epb < E) ? s + epb : E;
    for (int i = s + t; i < e_; i += 256) {
        int d = dst[i];
        int sv = src[i];
        int pos = atomicAdd(&cur[d >> 4], 1);   // LDS atomic
        pairs[pos] = make_int2(d, sv);
    }
}

// one WAVE per coarse bin: ballot-histogram counts, stable ranks. No atomics.
__global__ __launch_bounds__(256) void finalize_kernel(
    const int2* __restrict__ pairs, const int* __restrict__ gscan,
    int* __restrict__ offs, int* __restrict__ csr_src, int N, int E, int CB)
{
    const int wid = blockIdx.x * 4 + (threadIdx.x >> 6);   // bin index
    const int lane = threadIdx.x & 63;
    if (wid >= CB) return;                                 // wave-uniform exit

    const int s    = gscan[wid * 64];
    const int e_   = (wid + 1 < CB) ? gscan[(wid + 1) * 64] : E;
    const int base = wid * 16;
    const unsigned long long ltmask = (lane == 63) ? ~0ull >> 1
                                                   : (1ull << lane) - 1ull;

    int rc[16];
#pragma unroll
    for (int j = 0; j < 16; j++) rc[j] = 0;
    for (int c0 = s; c0 < e_; c0 += 64) {
        int i = c0 + lane;
        int d = (i < e_) ? pairs[i].x - base : -1;
#pragma unroll
        for (int j = 0; j < 16; j++)
            rc[j] += (int)__popcll(__ballot(d == j));
    }

    int pref[16];
    int run = s;
#pragma unroll
    for (int j = 0; j < 16; j++) { pref[j] = run; run += rc[j]; }
    int pref_v = 0;
#pragma unroll
    for (int j = 0; j < 16; j++) pref_v = (lane == j) ? pref[j] : pref_v;

    if (lane < 16 && base + lane < N) offs[base + lane] = pref_v;
    if (wid == CB - 1 && lane == 16) offs[N] = E;

    int rcv = 0;
    for (int c0 = s; c0 < e_; c0 += 64) {
        int i = c0 + lane;
        const bool act = i < e_;
        int2 pr = act ? pairs[i] : make_int2(base - 1, 0);
        int d = pr.x - base;
        unsigned long long msel = 0;
        int addcnt = 0;
#pragma unroll
        for (int j = 0; j < 16; j++) {
            unsigned long long m = __ballot(d == j);
            if (d == j) msel = m;
            if (lane == j) addcnt = (int)__popcll(m);
        }
        int subrank = (int)__popcll(msel & ltmask);
        int posbase = __builtin_amdgcn_ds_bpermute(d * 4, pref_v + rcv);
        if (act) csr_src[posbase + subrank] = pr.y;
        rcv += addcnt;
    }
}

// ---------------- fused GAT edge-softmax + aggregation (r15 form) ------------
// 16 lanes per dst node, 4 nodes per wave, 4 edges per group-iteration.
// Software-pipelined: batch i+1's p-row gathers issued at the top of
// iteration i; csr indices prefetched 2 batches ahead.
// EPI 0 (D=128): m2 = gelu(h+bvec) packed hi/lo bf16.  EPI 1 (D=64): fp32 out.
template <int D, int EPI>
__global__ __launch_bounds__(256) void gat_agg(
    const float* __restrict__ q, const unsigned short* __restrict__ p,
    const float* __restrict__ a, const float* __restrict__ bvec,
    const int* __restrict__ offs, const int* __restrict__ csr_src,
    float* __restrict__ out, unsigned short* __restrict__ mhi,
    unsigned short* __restrict__ mlo, int N)
{
    constexpr int VPL = D / 16;   // dims per lane: 8 (D=128) or 4 (D=64)
    const int t = threadIdx.x;
    const int lane = t & 63;
    const int sl = lane & 15;
    const int base = sl * VPL;
    const int node = blockIdx.x * 16 + ((t >> 6) << 2) + (lane >> 4);
    const bool valid = node < N;

    float qv[VPL], a6[VPL], a4[VPL], acc[VPL];
#pragma unroll
    for (int v = 0; v < VPL; v++) { qv[v] = 0.f; acc[v] = 0.f; }
    if (valid) {
        const float* qp = q + (size_t)node * D + base;
        float4 q0 = *reinterpret_cast<const float4*>(qp);
        qv[0] = q0.x; qv[1] = q0.y; qv[2] = q0.z; qv[3] = q0.w;
        if constexpr (VPL == 8) {
            float4 q1 = *reinterpret_cast<const float4*>(qp + 4);
            qv[4] = q1.x; qv[5] = q1.y; qv[6] = q1.z; qv[7] = q1.w;
        }
    }
#pragma unroll
    for (int v = 0; v < VPL; v++) {
        float av = a[base + v];
        a6[v] = 0.6f * av;
        a4[v] = 0.4f * av;
    }

    auto gather = [&](int s) -> uint4 {
        if constexpr (D == 128) {
            return *reinterpret_cast<const uint4*>(p + (size_t)s * 128 + base);
        } else {
            uint2 u = *reinterpret_cast<const uint2*>(p + (size_t)s * 64 + base);
            return make_uint4(u.x, u.y, 0u, 0u);
        }
    };
    auto unpack = [&](uint4 u, float* pv) {
        pv[0] = __uint_as_float(u.x << 16); pv[1] = __uint_as_float(u.x & 0xffff0000u);
        pv[2] = __uint_as_float(u.y << 16); pv[3] = __uint_as_float(u.y & 0xffff0000u);
        if constexpr (VPL == 8) {
            pv[4] = __uint_as_float(u.z << 16); pv[5] = __uint_as_float(u.z & 0xffff0000u);
            pv[6] = __uint_as_float(u.w << 16); pv[7] = __uint_as_float(u.w & 0xffff0000u);
        }
    };

    float denom = 0.f;
    int e  = valid ? offs[node] : 0;
    int e1 = valid ? offs[node + 1] : 0;

    int s0 = csr_src[(e + 0 < e1) ? e + 0 : 0];
    int s1 = csr_src[(e + 1 < e1) ? e + 1 : 0];
    int s2 = csr_src[(e + 2 < e1) ? e + 2 : 0];
    int s3 = csr_src[(e + 3 < e1) ? e + 3 : 0];
    uint4 uA0 = gather(s0), uA1 = gather(s1), uA2 = gather(s2), uA3 = gather(s3);
    int en = e + 4;
    int n0 = csr_src[(en + 0 < e1) ? en + 0 : 0];
    int n1 = csr_src[(en + 1 < e1) ? en + 1 : 0];
    int n2 = csr_src[(en + 2 < e1) ? en + 2 : 0];
    int n3 = csr_src[(en + 3 < e1) ? en + 3 : 0];

    while (__any(e < e1)) {
        const bool a0 = (e + 0) < e1, a1b = (e + 1) < e1,
                   a2 = (e + 2) < e1, a3 = (e + 3) < e1;

        uint4 v0 = gather(n0), v1 = gather(n1), v2 = gather(n2), v3 = gather(n3);

        const int em = en + 4;
        const int m0 = csr_src[(em + 0 < e1) ? em + 0 : 0];
        const int m1 = csr_src[(em + 1 < e1) ? em + 1 : 0];
        const int m2 = csr_src[(em + 2 < e1) ? em + 2 : 0];
        const int m3 = csr_src[(em + 3 < e1) ? em + 3 : 0];

        float pv[4][VPL];
        unpack(uA0, pv[0]); unpack(uA1, pv[1]); unpack(uA2, pv[2]); unpack(uA3, pv[3]);

        float pa0 = 0.f, pa1 = 0.f, pa2 = 0.f, pa3 = 0.f;
#pragma unroll
        for (int v = 0; v < VPL; v++) {
            float d0 = qv[v] + pv[0][v];
            float d1 = qv[v] + pv[1][v];
            float d2 = qv[v] + pv[2][v];
            float d3 = qv[v] + pv[3][v];
            pa0 = fmaf(d0, a6[v], pa0); pa0 = fmaf(fabsf(d0), a4[v], pa0);
            pa1 = fmaf(d1, a6[v], pa1); pa1 = fmaf(fabsf(d1), a4[v], pa1);
            pa2 = fmaf(d2, a6[v], pa2); pa2 = fmaf(fabsf(d2), a4[v], pa2);
            pa3 = fmaf(d3, a6[v], pa3); pa3 = fmaf(fabsf(d3), a4[v], pa3);
        }

        float r0 = row16_sum(pa0);
        float r1 = row16_sum(pa1);
        float r2 = row16_sum(pa2);
        float r3 = row16_sum(pa3);

        float esm0 = a0  ? __expf(r0) : 0.f;
        float esm1 = a1b ? __expf(r1) : 0.f;
        float esm2 = a2  ? __expf(r2) : 0.f;
        float esm3 = a3  ? __expf(r3) : 0.f;
        denom += (esm0 + esm1) + (esm2 + esm3);
#pragma unroll
        for (int v = 0; v < VPL; v++) {
            acc[v] = fmaf(esm0, pv[0][v], acc[v]);
            acc[v] = fmaf(esm1, pv[1][v], acc[v]);
            acc[v] = fmaf(esm2, pv[2][v], acc[v]);
            acc[v] = fmaf(esm3, pv[3][v], acc[v]);
        }

        uA0 = v0; uA1 = v1; uA2 = v2; uA3 = v3;
        n0 = m0; n1 = m1; n2 = m2; n3 = m3;
        e = en; en = em;
    }

    if (!valid) return;
    float inv = (denom != 0.f) ? 1.f / denom : 0.f;  // zero-degree -> agg = 0
    if constexpr (EPI == 0) {
        union { unsigned short us[8]; uint4 v; } H, L;
#pragma unroll
        for (int v = 0; v < VPL; v++) {
            float g = gelu_erf(acc[v] * inv + bvec[base + v]);
            H.us[v] = f2bf(g);
            L.us[v] = f2bf(g - bf2f(H.us[v]));
        }
        *reinterpret_cast<uint4*>(mhi + (size_t)node * 128 + base) = H.v;
        *reinterpret_cast<uint4*>(mlo + (size_t)node * 128 + base) = L.v;
    } else {
        union { float f[4]; float4 v; } O;
#pragma unroll
        for (int v = 0; v < VPL; v++) O.f[v] = acc[v] * inv + bvec[base + v];
        *reinterpret_cast<float4*>(out + (size_t)node * D + base) = O.v;
    }
}

// ---------------- launch ------------------------------------------------------
extern "C" void kernel_launch(void* const* d_in, const int* in_sizes, int n_in,
                              void* d_out, int out_size, void* d_ws, size_t ws_size,
                              hipStream_t stream)
{
    const float* x     = (const float*)d_in[0];
    const float* W0    = (const float*)d_in[1];
    const float* b0    = (const float*)d_in[2];
    const float* Wq1   = (const float*)d_in[3];
    const float* bq1   = (const float*)d_in[4];
    const float* Wp1   = (const float*)d_in[5];
    const float* bp1   = (const float*)d_in[6];
    const float* a1    = (const float*)d_in[7];
    const float* bg2   = (const float*)d_in[8];
    const float* Wq2   = (const float*)d_in[9];
    const float* bq2   = (const float*)d_in[10];
    const float* Wp2   = (const float*)d_in[11];
    const float* bp2   = (const float*)d_in[12];
    const float* a2    = (const float*)d_in[13];
    const float* b_out = (const float*)d_in[14];
    const int*   src   = (const int*)d_in[15];
    const int*   dst   = (const int*)d_in[16];

    const int N = in_sizes[0] / 128;
    const int E = in_sizes[15];
    float* out = (float*)d_out;

    // workspace carve
    float* q_buf        = (float*)d_ws;                      // N*128 f32 (q1, then q2)
    unsigned short* pb  = (unsigned short*)(q_buf + (size_t)N * 128);  // N*128 bf16 (p1, then p2)
    unsigned short* Mhi = pb + (size_t)N * 128;              // m2 hi
    unsigned short* Mlo = Mhi + (size_t)N * 128;             // m2 lo
    unsigned short* P0  = Mlo + (size_t)N * 128;
    unsigned short* Pq1 = P0  + 128 * 128 * 2;
    unsigned short* Pp1 = Pq1 + 128 * 128 * 2;
    unsigned short* Pq2 = Pp1 + 128 * 128 * 2;
    unsigned short* Pp2 = Pq2 + 128 * 64 * 2;
    int* offs    = (int*)(Pp2 + 128 * 64 * 2);
    int* csr_src = offs + (N + 2);
    const int CB = (N + 15) / 16;          // coarse bins
    const int M  = CB * 64;
    int* gh    = csr_src + E;
    int* gscan = gh + M;
    int* bsum  = gscan + M;                // 1024 ints
    // pairs aliases q_buf (dead before gemm_fused01 writes q1)
    int2* pairs = (int2*)q_buf;

    const int NB1 = (M + 255) / 256;       // <= 1024

    // 1) weight prepack
    pack_w<<<dim3(64, 5), 256, 0, stream>>>(W0, Wq1, Wp1, Wq2, Wp2,
                                            P0, Pq1, Pp1, Pq2, Pp2);
    // 2-7) CSR build (atomic-free two-level counting sort)
    hist_coarse<<<64, 256, 0, stream>>>(dst, gh, E, CB);
    scan1_kernel<<<NB1, 256, 0, stream>>>(gh, gscan, bsum, M);
    scan2_kernel<<<1, 1024, 0, stream>>>(bsum, NB1);
    scan3_kernel<<<NB1, 256, 0, stream>>>(gscan, bsum, M);
    scatter_coarse<<<64, 256, 0, stream>>>(src, dst, gscan, pairs, E, CB);
    finalize_kernel<<<(CB + 3) / 4, 256, 0, stream>>>(pairs, gscan, offs, csr_src, N, E, CB);

    const int GB64 = (N + 63) / 64;
    const int GGAT = (N + 15) / 16;

    // 8) layer0 GEMM + gelu + layer1 projections (m1 stays in LDS)
    gemm_fused01<<<GB64, 256, 0, stream>>>(
        x, P0, b0, Pq1, bq1, Pp1, bp1, q_buf, pb, N);
    // 9) layer1 GAT -> m2 = gelu(h1 + bg2) -> Mhi/Mlo
    gat_agg<128, 0><<<GGAT, 256, 0, stream>>>(
        q_buf, pb, a1, bg2, offs, csr_src,
        nullptr, Mhi, Mlo, N);
    // 10) layer2 projections: q2 fp32 + p2 bf16 (overwrite q_buf/pb)
    mfma_gemm64<<<GB64, 256, 0, stream>>>(
        Mhi, Mlo, Pq2, bq2, Pp2, bp2,
        q_buf, pb, N);
    // 11) layer2 GAT + b_out -> d_out
    gat_agg<64, 1><<<GGAT, 256, 0, stream>>>(
        q_buf, pb, a2, b_out, offs, csr_src,
        out, nullptr, nullptr, N);
}